// Round 11
// baseline (3586.526 us; speedup 1.0000x reference)
//
#include <hip/hip_runtime.h>
#include <hip/hip_bf16.h>
#include <stdint.h>

typedef __attribute__((ext_vector_type(4))) float f32x4;
typedef __attribute__((ext_vector_type(8))) short short8;
typedef __attribute__((ext_vector_type(4))) short short4v;
typedef __attribute__((ext_vector_type(4))) int int4v;

// ---------------- workspace layout (bytes) ----------------
#define OFF_XBF  ((size_t)0)            // [8192][1024] bf16 = 16777216
#define OFF_WIT  ((size_t)16777216)     // [2*4096][1024] bf16 (dead after k_gemm; htag reuses)
#define OFF_WHT  ((size_t)33554432)     // [2*4096][1024] bf16 = 16777216
#define OFF_XG   ((size_t)50331648)     // [8192][8192] bf16 = 134217728
#define OFF_BIAS ((size_t)184811520)    // [8192] f32 = 32768
#define OFF_LEN  ((size_t)184844288)    // [32] i32
// htag: [2 parity][2 dir][64 prod][32 batch][16 col] u32 (bf16<<16|tag) = 524288 B at OFF_WIT

__device__ __forceinline__ short f2bf(float f) {
  union { float f; uint32_t u; } v; v.f = f;
  uint32_t u = v.u;
  uint32_t r = (u + 0x7fffu + ((u >> 16) & 1u)) >> 16;
  return (short)r;
}
__device__ __forceinline__ float bf2f(short s) {
  union { uint32_t u; float f; } v; v.u = ((uint32_t)(uint16_t)s) << 16;
  return v.f;
}
__device__ __forceinline__ float sigf(float z) {
  float e = __builtin_amdgcn_exp2f(z * -1.44269504f);
  return __builtin_amdgcn_rcpf(1.f + e);
}
__device__ __forceinline__ float tanhfast(float z) {
  float e = __builtin_amdgcn_exp2f(z * -2.88539008f);
  return fmaf(__builtin_amdgcn_rcpf(1.f + e), 2.f, -1.f);
}

// ---------------- lengths ----------------
__global__ void k_len(const int* __restrict__ mask, int* __restrict__ len) {
  int b = threadIdx.x;
  if (b < 32) {
    int s = 0;
    for (int t = 0; t < 256; t++) s += mask[b * 256 + t];
    len[b] = s;
  }
}

// ---------------- x -> bf16, [B,T,D] -> [(t*32+b), D] ----------------
__global__ void k_xconv(const float* __restrict__ x, short* __restrict__ xbf) {
  int bid = blockIdx.x;              // 0..8191 = b*256 + t
  int b = bid >> 8, t = bid & 255;
  int d = threadIdx.x * 4;
  const float* sp = x + ((size_t)bid) * 1024 + d;
  float4 v = *(const float4*)sp;
  short4v o;
  o.x = f2bf(v.x); o.y = f2bf(v.y); o.z = f2bf(v.z); o.w = f2bf(v.w);
  *(short4v*)(xbf + ((size_t)(t * 32 + b)) * 1024 + d) = o;
}

// ------- weights: transpose [k][4096] f32 -> [n_perm][k] bf16, gate-interleaved perm -------
// perm: p = g4*16 + gate*4 + h4  <->  orig col c = gate*1024 + g4*4 + h4
__global__ void k_wprep(const float* __restrict__ Wi_f, const float* __restrict__ Wi_b,
                        const float* __restrict__ Wh_f, const float* __restrict__ Wh_b,
                        short* __restrict__ WiT, short* __restrict__ WhT) {
  __shared__ short ldsT[64 * 72];
  int id = blockIdx.x;               // 4096 blocks
  int which = id >> 11, dir = (id >> 10) & 1, tile = id & 1023;
  int kt = (tile >> 6) * 64, c0 = (tile & 63) * 64;
  const float* src = (which == 0) ? (dir == 0 ? Wi_f : Wi_b)
                                  : (dir == 0 ? Wh_f : Wh_b);
  short* dst = (which == 0) ? WiT : WhT;
  int tid = threadIdx.x;
#pragma unroll 4
  for (int i = 0; i < 16; i++) {
    int idx = i * 256 + tid;
    int kk = idx >> 6, cc = idx & 63;
    float v = src[(size_t)(kt + kk) * 4096 + c0 + cc];
    ldsT[cc * 72 + kk] = f2bf(v);    // transposed store
  }
  __syncthreads();
  int rowc = tid >> 2, part = tid & 3;
  int cg = c0 + rowc;
  int gate = cg >> 10, hc = cg & 1023;
  int p = (hc >> 2) * 16 + gate * 4 + (hc & 3);
  int n = dir * 4096 + p;
  short8 v0 = *(short8*)&ldsT[rowc * 72 + part * 16];
  short8 v1 = *(short8*)&ldsT[rowc * 72 + part * 16 + 8];
  *(short8*)(dst + (size_t)n * 1024 + kt + part * 16) = v0;
  *(short8*)(dst + (size_t)n * 1024 + kt + part * 16 + 8) = v1;
}

// ---------------- bias permute ----------------
__global__ void k_bias(const float* __restrict__ bf_, const float* __restrict__ bb_,
                       float* __restrict__ bp) {
  int n = blockIdx.x * 256 + threadIdx.x;   // 0..8191
  int dir = n >> 12, p = n & 4095;
  int gate = (p >> 2) & 3, g4 = p >> 4, h4 = p & 3;
  int c = gate * 1024 + g4 * 4 + h4;
  bp[n] = (dir == 0 ? bf_ : bb_)[c];
}

// ---------------- XG = xbf @ WiT^T + bias : [8192][8192] bf16 ----------------
__global__ void k_gemm(const short* __restrict__ Abf,
                       const short* __restrict__ Bbf,
                       const float* __restrict__ bias,
                       short* __restrict__ C) {
  __shared__ char Ash[128 * 144];
  __shared__ char Bsh[128 * 144];
  const int tid = threadIdx.x;
  const int lane = tid & 63, wid = tid >> 6;
  const int wm = wid >> 1, wn = wid & 1;
  const int l15 = lane & 15, lg = lane >> 4;
  const int m0 = blockIdx.y * 128, n0 = blockIdx.x * 128;

  f32x4 acc[4][4];
#pragma unroll
  for (int i = 0; i < 4; i++)
#pragma unroll
    for (int j = 0; j < 4; j++) acc[i][j] = (f32x4){0.f, 0.f, 0.f, 0.f};

  for (int kt = 0; kt < 1024; kt += 64) {
#pragma unroll
    for (int i = 0; i < 4; i++) {
      int chunk = i * 256 + tid;
      int row = chunk >> 3, kc = chunk & 7;
      *(short8*)(Ash + row * 144 + kc * 16) =
          *(const short8*)(Abf + (size_t)(m0 + row) * 1024 + kt + kc * 8);
      *(short8*)(Bsh + row * 144 + kc * 16) =
          *(const short8*)(Bbf + (size_t)(n0 + row) * 1024 + kt + kc * 8);
    }
    __syncthreads();
#pragma unroll
    for (int kk = 0; kk < 2; kk++) {
      short8 af[4], bfv[4];
#pragma unroll
      for (int mt = 0; mt < 4; mt++)
        af[mt] = *(const short8*)(Ash + (wm * 64 + mt * 16 + l15) * 144 + kk * 64 + lg * 16);
#pragma unroll
      for (int ntc = 0; ntc < 4; ntc++)
        bfv[ntc] = *(const short8*)(Bsh + (wn * 64 + ntc * 16 + l15) * 144 + kk * 64 + lg * 16);
#pragma unroll
      for (int mt = 0; mt < 4; mt++)
#pragma unroll
        for (int ntc = 0; ntc < 4; ntc++)
          acc[mt][ntc] = __builtin_amdgcn_mfma_f32_16x16x32_bf16(af[mt], bfv[ntc], acc[mt][ntc], 0, 0, 0);
    }
    __syncthreads();
  }
  float bs[4];
#pragma unroll
  for (int ntc = 0; ntc < 4; ntc++) bs[ntc] = bias[n0 + wn * 64 + ntc * 16 + l15];
#pragma unroll
  for (int mt = 0; mt < 4; mt++) {
    int row = m0 + wm * 64 + mt * 16 + lg * 4;
#pragma unroll
    for (int ntc = 0; ntc < 4; ntc++) {
      int col = n0 + wn * 64 + ntc * 16 + l15;
#pragma unroll
      for (int r = 0; r < 4; r++)
        C[(size_t)(row + r) * 8192 + col] = f2bf(acc[mt][ntc][r] + bs[ntc]);
    }
  }
}

// ---------------- persistent recurrence (tag-in-data, pipelined per-wave stage) ----
// 128 blocks x 512 thr (8 waves). dir = bid>>6, nblk = bid&63 owns permuted
// z-cols [nblk*64,+64) = h-cols [nblk*16,+16). Wave (mt,nt): 16 batches x 16 cols.
// htag layout: [parity][dir][producer][32 batch][16 col] u32 = bf16<<16 | step_tag.
// Publish: wave0 expands its 1KB Pub to 2KB tagged, 2x dwordx4 sc0 sc1 stores,
// NO drain, NO flag. Consume: wave w loads its 8 producers' regions (2 loads/lane),
// verifies tags in-register, retries only failed regions -> detection IS the load.
__global__ void __launch_bounds__(512, 1) k_recur(
    const short* __restrict__ XG,    // [8192][8192] bf16
    const short* __restrict__ WhT,   // [2*4096][1024] bf16
    const int* __restrict__ len,
    unsigned int* __restrict__ htag, // [2][2][64][32][16] u32
    float* __restrict__ out) {       // [32][256][2048] f32
  __shared__ char Hld[66560];        // 64KB staged h + 1KB publish buffer
  char* Pub = Hld + 65536;
  char* tb_base = (char*)htag;
  const int tid = threadIdx.x;
  const int lane = tid & 63;
  const int wid = tid >> 6;
  const int bidx = blockIdx.x;
  const int dir = bidx >> 6;
  const int nblk = bidx & 63;
  const int mt = wid >> 2, nt = wid & 3;
  const int l15 = lane & 15, lg = lane >> 4;

  // B-fragments (Wh columns), resident in registers for all 256 steps
  const int ncol = dir * 4096 + nblk * 64 + nt * 16 + l15;
  const short* wrow = WhT + (size_t)ncol * 1024;
  short8 bfr[32];
#pragma unroll
  for (int kk = 0; kk < 32; kk++)
    bfr[kk] = *(const short8*)(wrow + kk * 32 + lg * 8);

  float c_reg[4] = {0.f, 0.f, 0.f, 0.f};
  int lenv[4];
#pragma unroll
  for (int r = 0; r < 4; r++) lenv[r] = len[mt * 16 + lg * 4 + r];

  const int c4 = l15;
  const int gate = c4 >> 2;
  const int brow = mt * 16 + l15;
  const int sw = (brow & 7) << 4;
  const int abase = brow * 2048 + (lg << 4);
  const int hcol0 = nblk * 16 + nt * 4;

  // prefetch XG for t=0
  float xg_pf[4];
#pragma unroll
  for (int r = 0; r < 4; r++) {
    int b_r = mt * 16 + lg * 4 + r;
    int tt = (dir == 0) ? 0 : ((lenv[r] - 1) & 255);
    xg_pf[r] = bf2f(XG[(size_t)(tt * 32 + b_r) * 8192 + ncol]);
  }

  // per-wave stage constants: wave wid stages producers [wid*8, wid*8+8)
  const int myb = lane >> 1;                  // batch row this lane handles
  const int mysw = (myb & 7) << 4;
  const int mybase = myb * 2048 + (lane & 1) * 16;   // LDS dest (untagged 16B half)
  const int srcoff = myb * 64 + (lane & 1) * 32;     // tagged src (32B half of 64B row)

  for (int t = 0; t < 256; t++) {
    const char* tb  = tb_base + (size_t)((t & 1) * 2 + dir) * 131072;
    char* tbn       = tb_base + (size_t)(((t + 1) & 1) * 2 + dir) * 131072;
    const uint32_t exp = (uint32_t)t;

    // ---- stage: tagged load + per-region retry (detection fused into load) ----
    {
      int4v v[8][2];
      const char* a0 = tb + srcoff;
#pragma unroll
      for (int j = 0; j < 8; j++) {
        const char* a = a0 + (wid * 8 + j) * 2048;
        asm volatile("global_load_dwordx4 %0, %1, off sc0 sc1" : "=v"(v[j][0]) : "v"(a));
        asm volatile("global_load_dwordx4 %0, %1, off sc0 sc1" : "=v"(v[j][1]) : "v"(a + 16));
      }
      asm volatile("s_waitcnt vmcnt(0)" ::: "memory");
      __builtin_amdgcn_sched_barrier(0);
      for (;;) {
        uint32_t bad = 0;
#pragma unroll
        for (int j = 0; j < 8; j++) {
          uint32_t m = (((uint32_t)v[j][0].x ^ exp) | ((uint32_t)v[j][0].y ^ exp) |
                        ((uint32_t)v[j][0].z ^ exp) | ((uint32_t)v[j][0].w ^ exp) |
                        ((uint32_t)v[j][1].x ^ exp) | ((uint32_t)v[j][1].y ^ exp) |
                        ((uint32_t)v[j][1].z ^ exp) | ((uint32_t)v[j][1].w ^ exp)) & 0xffffu;
          if (m) bad |= 1u << j;
        }
        if (!bad) break;
#pragma unroll
        for (int j = 0; j < 8; j++)
          if (bad & (1u << j)) {
            const char* a = a0 + (wid * 8 + j) * 2048;
            asm volatile("global_load_dwordx4 %0, %1, off sc0 sc1" : "=v"(v[j][0]) : "v"(a));
            asm volatile("global_load_dwordx4 %0, %1, off sc0 sc1" : "=v"(v[j][1]) : "v"(a + 16));
          }
        asm volatile("s_waitcnt vmcnt(0)" ::: "memory");
        __builtin_amdgcn_sched_barrier(0);
      }
      // strip tags -> bf16 16B, write LDS (same pattern as untagged round)
#pragma unroll
      for (int j = 0; j < 8; j++) {
        int4v w;
        w.x = (int)((((uint32_t)v[j][0].x) >> 16) | (((uint32_t)v[j][0].y) & 0xffff0000u));
        w.y = (int)((((uint32_t)v[j][0].z) >> 16) | (((uint32_t)v[j][0].w) & 0xffff0000u));
        w.z = (int)((((uint32_t)v[j][1].x) >> 16) | (((uint32_t)v[j][1].y) & 0xffff0000u));
        w.w = (int)((((uint32_t)v[j][1].z) >> 16) | (((uint32_t)v[j][1].w) & 0xffff0000u));
        int off = (mybase + (wid * 8 + j) * 32) ^ mysw;
        *(int4v*)(Hld + off) = w;
      }
    }
    __syncthreads();

    // ---- two independent MFMA chains ----
    f32x4 accA = (f32x4){0.f, 0.f, 0.f, 0.f};
    f32x4 accB = (f32x4){0.f, 0.f, 0.f, 0.f};
#pragma unroll
    for (int kk = 0; kk < 16; kk++) {
      short8 afA = *(const short8*)(Hld + ((abase + kk * 64) ^ sw));
      short8 afB = *(const short8*)(Hld + ((abase + (kk + 16) * 64) ^ sw));
      accA = __builtin_amdgcn_mfma_f32_16x16x32_bf16(afA, bfr[kk], accA, 0, 0, 0);
      accB = __builtin_amdgcn_mfma_f32_16x16x32_bf16(afB, bfr[kk + 16], accB, 0, 0, 0);
    }

    // ---- gates (fast exp2 math); h -> Pub (LDS) ----
    f32x4 hsave[4];
#pragma unroll
    for (int r = 0; r < 4; r++) {
      int b_r = mt * 16 + lg * 4 + r;
      float z = accA[r] + accB[r] + xg_pf[r];
      float s = (gate == 2) ? tanhfast(z) : sigf(z);
      float x8 = __shfl_xor(s, 8);     // i<->g, f<->o
      float pI = s * x8;               // on i-lanes: sig(i)*tanh(g)
      float v = (gate == 0) ? pI : s;
      float x4 = __shfl_xor(v, 4);     // i-lane receives sig(f)
      float o4 = __shfl_xor(x8, 4);    // i-lane receives sig(o)
      float cn = fmaf(x4, c_reg[r], pI);
      float h = o4 * tanhfast(cn);
      if (c4 < 4) c_reg[r] = cn;
      uint32_t hb16 = (uint32_t)(uint16_t)f2bf(h);
      uint32_t p0 = hb16 | (__shfl_xor(hb16, 1) << 16);
      uint32_t q  = __shfl_xor(p0, 2);
      if (c4 == 0) {
        unsigned long long p = (unsigned long long)p0 | ((unsigned long long)q << 32);
        *(unsigned long long*)(Pub + b_r * 32 + nt * 8) = p;
        hsave[r].x = bf2f((short)(p0 & 0xffff));
        hsave[r].y = bf2f((short)(p0 >> 16));
        hsave[r].z = bf2f((short)(q & 0xffff));
        hsave[r].w = bf2f((short)(q >> 16));
      }
    }
    __syncthreads();   // Pub complete; Hld MFMA reads complete

    // ---- publish: wave0 expands Pub to tagged, fire-and-forget stores ----
    if (wid == 0) {
      int4v pv = *(const int4v*)(Pub + lane * 16);
      uint32_t tg = (uint32_t)(t + 1);
      int4v e0, e1;
      e0.x = (int)((((uint32_t)pv.x) << 16) | tg);
      e0.y = (int)((((uint32_t)pv.x) & 0xffff0000u) | tg);
      e0.z = (int)((((uint32_t)pv.y) << 16) | tg);
      e0.w = (int)((((uint32_t)pv.y) & 0xffff0000u) | tg);
      e1.x = (int)((((uint32_t)pv.z) << 16) | tg);
      e1.y = (int)((((uint32_t)pv.z) & 0xffff0000u) | tg);
      e1.z = (int)((((uint32_t)pv.w) << 16) | tg);
      e1.w = (int)((((uint32_t)pv.w) & 0xffff0000u) | tg);
      char* d0 = tbn + nblk * 2048 + (lane >> 1) * 64 + (lane & 1) * 32;
      asm volatile("global_store_dwordx4 %0, %1, off sc0 sc1" :: "v"(d0), "v"(e0) : "memory");
      asm volatile("global_store_dwordx4 %0, %1, off sc0 sc1" :: "v"(d0 + 16), "v"(e1) : "memory");
    }
    __builtin_amdgcn_sched_barrier(0);

    // ---- deferred (shadow): out stores + XG prefetch t+1 ----
    if (c4 == 0) {
#pragma unroll
      for (int r = 0; r < 4; r++) {
        int b_r = mt * 16 + lg * 4 + r;
        int tt = (dir == 0) ? t : ((lenv[r] - 1 - t) & 255);
        *(f32x4*)(out + ((size_t)b_r * 256 + tt) * 2048 + dir * 1024 + hcol0) = hsave[r];
      }
    }
    int tn = (t < 255) ? t + 1 : 255;
#pragma unroll
    for (int r = 0; r < 4; r++) {
      int b_r = mt * 16 + lg * 4 + r;
      int tt = (dir == 0) ? tn : ((lenv[r] - 1 - tn) & 255);
      xg_pf[r] = bf2f(XG[(size_t)(tt * 32 + b_r) * 8192 + ncol]);
    }
  }
}

extern "C" void kernel_launch(void* const* d_in, const int* in_sizes, int n_in,
                              void* d_out, int out_size, void* d_ws, size_t ws_size,
                              hipStream_t stream) {
  const float* x    = (const float*)d_in[0];
  const int*   mask = (const int*)d_in[1];
  const float* Wi_f = (const float*)d_in[2];
  const float* Wh_f = (const float*)d_in[3];
  const float* b_f  = (const float*)d_in[4];
  const float* Wi_b = (const float*)d_in[5];
  const float* Wh_b = (const float*)d_in[6];
  const float* b_b  = (const float*)d_in[7];
  float* out = (float*)d_out;
  char* ws = (char*)d_ws;

  short* xbf  = (short*)(ws + OFF_XBF);
  short* WiT  = (short*)(ws + OFF_WIT);
  short* WhT  = (short*)(ws + OFF_WHT);
  short* XG   = (short*)(ws + OFF_XG);
  float* bp   = (float*)(ws + OFF_BIAS);
  int*   len  = (int*)(ws + OFF_LEN);
  unsigned int* htag = (unsigned int*)(ws + OFF_WIT);  // reuses WiT after k_gemm

  k_len<<<1, 64, 0, stream>>>(mask, len);
  k_xconv<<<8192, 256, 0, stream>>>(x, xbf);
  k_wprep<<<4096, 256, 0, stream>>>(Wi_f, Wi_b, Wh_f, Wh_b, WiT, WhT);
  k_bias<<<32, 256, 0, stream>>>(b_f, b_b, bp);

  dim3 g(64, 64);
  k_gemm<<<g, 256, 0, stream>>>(xbf, WiT, bp, XG);

  // WiT dead from here; zero tagged h buffer (tag 0 == step-0, h == 0.0)
  hipMemsetAsync(htag, 0, 524288, stream);

  k_recur<<<128, 512, 0, stream>>>(XG, WhT, len, htag, out);
}

// Round 12
// 2269.409 us; speedup vs baseline: 1.5804x; 1.5804x over previous
//
#include <hip/hip_runtime.h>
#include <hip/hip_bf16.h>
#include <stdint.h>

typedef __attribute__((ext_vector_type(4))) float f32x4;
typedef __attribute__((ext_vector_type(8))) short short8;
typedef __attribute__((ext_vector_type(4))) short short4v;
typedef __attribute__((ext_vector_type(4))) int int4v;

// ---------------- workspace layout (bytes) ----------------
#define OFF_XBF  ((size_t)0)            // [8192][1024] bf16 = 16777216
#define OFF_WIT  ((size_t)16777216)     // [2*4096][1024] bf16 (dead after k_gemm; htag reuses)
#define OFF_WHT  ((size_t)33554432)     // [2*4096][1024] bf16 = 16777216
#define OFF_XG   ((size_t)50331648)     // [8192][8192] bf16 = 134217728
#define OFF_BIAS ((size_t)184811520)    // [8192] f32 = 32768
#define OFF_LEN  ((size_t)184844288)    // [32] i32
// htag: [2 parity][2 dir][64 prod][32 batch][16 col] u32 (bf16<<16|tag) = 524288 B at OFF_WIT

__device__ __forceinline__ short f2bf(float f) {
  union { float f; uint32_t u; } v; v.f = f;
  uint32_t u = v.u;
  uint32_t r = (u + 0x7fffu + ((u >> 16) & 1u)) >> 16;
  return (short)r;
}
__device__ __forceinline__ float bf2f(short s) {
  union { uint32_t u; float f; } v; v.u = ((uint32_t)(uint16_t)s) << 16;
  return v.f;
}
__device__ __forceinline__ float sigf(float z) {
  float e = __builtin_amdgcn_exp2f(z * -1.44269504f);
  return __builtin_amdgcn_rcpf(1.f + e);
}
__device__ __forceinline__ float tanhfast(float z) {
  float e = __builtin_amdgcn_exp2f(z * -2.88539008f);
  return fmaf(__builtin_amdgcn_rcpf(1.f + e), 2.f, -1.f);
}

// ---------------- lengths ----------------
__global__ void k_len(const int* __restrict__ mask, int* __restrict__ len) {
  int b = threadIdx.x;
  if (b < 32) {
    int s = 0;
    for (int t = 0; t < 256; t++) s += mask[b * 256 + t];
    len[b] = s;
  }
}

// ---------------- x -> bf16, [B,T,D] -> [(t*32+b), D] ----------------
__global__ void k_xconv(const float* __restrict__ x, short* __restrict__ xbf) {
  int bid = blockIdx.x;              // 0..8191 = b*256 + t
  int b = bid >> 8, t = bid & 255;
  int d = threadIdx.x * 4;
  const float* sp = x + ((size_t)bid) * 1024 + d;
  float4 v = *(const float4*)sp;
  short4v o;
  o.x = f2bf(v.x); o.y = f2bf(v.y); o.z = f2bf(v.z); o.w = f2bf(v.w);
  *(short4v*)(xbf + ((size_t)(t * 32 + b)) * 1024 + d) = o;
}

// ------- weights: transpose [k][4096] f32 -> [n_perm][k] bf16, gate-interleaved perm -------
// perm: p = g4*16 + gate*4 + h4  <->  orig col c = gate*1024 + g4*4 + h4
__global__ void k_wprep(const float* __restrict__ Wi_f, const float* __restrict__ Wi_b,
                        const float* __restrict__ Wh_f, const float* __restrict__ Wh_b,
                        short* __restrict__ WiT, short* __restrict__ WhT) {
  __shared__ short ldsT[64 * 72];
  int id = blockIdx.x;               // 4096 blocks
  int which = id >> 11, dir = (id >> 10) & 1, tile = id & 1023;
  int kt = (tile >> 6) * 64, c0 = (tile & 63) * 64;
  const float* src = (which == 0) ? (dir == 0 ? Wi_f : Wi_b)
                                  : (dir == 0 ? Wh_f : Wh_b);
  short* dst = (which == 0) ? WiT : WhT;
  int tid = threadIdx.x;
#pragma unroll 4
  for (int i = 0; i < 16; i++) {
    int idx = i * 256 + tid;
    int kk = idx >> 6, cc = idx & 63;
    float v = src[(size_t)(kt + kk) * 4096 + c0 + cc];
    ldsT[cc * 72 + kk] = f2bf(v);    // transposed store
  }
  __syncthreads();
  int rowc = tid >> 2, part = tid & 3;
  int cg = c0 + rowc;
  int gate = cg >> 10, hc = cg & 1023;
  int p = (hc >> 2) * 16 + gate * 4 + (hc & 3);
  int n = dir * 4096 + p;
  short8 v0 = *(short8*)&ldsT[rowc * 72 + part * 16];
  short8 v1 = *(short8*)&ldsT[rowc * 72 + part * 16 + 8];
  *(short8*)(dst + (size_t)n * 1024 + kt + part * 16) = v0;
  *(short8*)(dst + (size_t)n * 1024 + kt + part * 16 + 8) = v1;
}

// ---------------- bias permute ----------------
__global__ void k_bias(const float* __restrict__ bf_, const float* __restrict__ bb_,
                       float* __restrict__ bp) {
  int n = blockIdx.x * 256 + threadIdx.x;   // 0..8191
  int dir = n >> 12, p = n & 4095;
  int gate = (p >> 2) & 3, g4 = p >> 4, h4 = p & 3;
  int c = gate * 1024 + g4 * 4 + h4;
  bp[n] = (dir == 0 ? bf_ : bb_)[c];
}

// ---------------- XG = xbf @ WiT^T + bias : [8192][8192] bf16 ----------------
__global__ void k_gemm(const short* __restrict__ Abf,
                       const short* __restrict__ Bbf,
                       const float* __restrict__ bias,
                       short* __restrict__ C) {
  __shared__ char Ash[128 * 144];
  __shared__ char Bsh[128 * 144];
  const int tid = threadIdx.x;
  const int lane = tid & 63, wid = tid >> 6;
  const int wm = wid >> 1, wn = wid & 1;
  const int l15 = lane & 15, lg = lane >> 4;
  const int m0 = blockIdx.y * 128, n0 = blockIdx.x * 128;

  f32x4 acc[4][4];
#pragma unroll
  for (int i = 0; i < 4; i++)
#pragma unroll
    for (int j = 0; j < 4; j++) acc[i][j] = (f32x4){0.f, 0.f, 0.f, 0.f};

  for (int kt = 0; kt < 1024; kt += 64) {
#pragma unroll
    for (int i = 0; i < 4; i++) {
      int chunk = i * 256 + tid;
      int row = chunk >> 3, kc = chunk & 7;
      *(short8*)(Ash + row * 144 + kc * 16) =
          *(const short8*)(Abf + (size_t)(m0 + row) * 1024 + kt + kc * 8);
      *(short8*)(Bsh + row * 144 + kc * 16) =
          *(const short8*)(Bbf + (size_t)(n0 + row) * 1024 + kt + kc * 8);
    }
    __syncthreads();
#pragma unroll
    for (int kk = 0; kk < 2; kk++) {
      short8 af[4], bfv[4];
#pragma unroll
      for (int mt = 0; mt < 4; mt++)
        af[mt] = *(const short8*)(Ash + (wm * 64 + mt * 16 + l15) * 144 + kk * 64 + lg * 16);
#pragma unroll
      for (int ntc = 0; ntc < 4; ntc++)
        bfv[ntc] = *(const short8*)(Bsh + (wn * 64 + ntc * 16 + l15) * 144 + kk * 64 + lg * 16);
#pragma unroll
      for (int mt = 0; mt < 4; mt++)
#pragma unroll
        for (int ntc = 0; ntc < 4; ntc++)
          acc[mt][ntc] = __builtin_amdgcn_mfma_f32_16x16x32_bf16(af[mt], bfv[ntc], acc[mt][ntc], 0, 0, 0);
    }
    __syncthreads();
  }
  float bs[4];
#pragma unroll
  for (int ntc = 0; ntc < 4; ntc++) bs[ntc] = bias[n0 + wn * 64 + ntc * 16 + l15];
#pragma unroll
  for (int mt = 0; mt < 4; mt++) {
    int row = m0 + wm * 64 + mt * 16 + lg * 4;
#pragma unroll
    for (int ntc = 0; ntc < 4; ntc++) {
      int col = n0 + wn * 64 + ntc * 16 + l15;
#pragma unroll
      for (int r = 0; r < 4; r++)
        C[(size_t)(row + r) * 8192 + col] = f2bf(acc[mt][ntc][r] + bs[ntc]);
    }
  }
}

// ---------------- persistent recurrence (tags v2: drained publish + throttled retry) ----
// 128 blocks x 512 thr (8 waves). dir = bid>>6, nblk = bid&63 owns permuted
// z-cols [nblk*64,+64) = h-cols [nblk*16,+16). Wave (mt,nt): 16 batches x 16 cols.
// htag layout: [parity][dir][producer][32 batch][16 col] u32 = bf16<<16 | step_tag.
// Publish: each wave stores its own 16 tagged 16B chunks right after gates (no
// barrier, no repack), then drains vmcnt(0) -> prompt MALL commit (R11's missing
// piece). Consume: one speculative tagged load round (detect fused into load);
// failed 32B chunks retry with s_sleep(8) backoff after round 2.
__global__ void __launch_bounds__(512, 1) k_recur(
    const short* __restrict__ XG,    // [8192][8192] bf16
    const short* __restrict__ WhT,   // [2*4096][1024] bf16
    const int* __restrict__ len,
    unsigned int* __restrict__ htag, // [2][2][64][32][16] u32
    float* __restrict__ out) {       // [32][256][2048] f32
  __shared__ char Hld[65536];
  char* tb_base = (char*)htag;
  const int tid = threadIdx.x;
  const int lane = tid & 63;
  const int wid = tid >> 6;
  const int bidx = blockIdx.x;
  const int dir = bidx >> 6;
  const int nblk = bidx & 63;
  const int mt = wid >> 2, nt = wid & 3;
  const int l15 = lane & 15, lg = lane >> 4;

  // B-fragments (Wh columns), resident in registers for all 256 steps
  const int ncol = dir * 4096 + nblk * 64 + nt * 16 + l15;
  const short* wrow = WhT + (size_t)ncol * 1024;
  short8 bfr[32];
#pragma unroll
  for (int kk = 0; kk < 32; kk++)
    bfr[kk] = *(const short8*)(wrow + kk * 32 + lg * 8);

  float c_reg[4] = {0.f, 0.f, 0.f, 0.f};
  int lenv[4];
#pragma unroll
  for (int r = 0; r < 4; r++) lenv[r] = len[mt * 16 + lg * 4 + r];

  const int c4 = l15;
  const int gate = c4 >> 2;
  const int brow = mt * 16 + l15;
  const int sw = (brow & 7) << 4;
  const int abase = brow * 2048 + (lg << 4);
  const int hcol0 = nblk * 16 + nt * 4;

  // prefetch XG for t=0
  float xg_pf[4];
#pragma unroll
  for (int r = 0; r < 4; r++) {
    int b_r = mt * 16 + lg * 4 + r;
    int tt = (dir == 0) ? 0 : ((lenv[r] - 1) & 255);
    xg_pf[r] = bf2f(XG[(size_t)(tt * 32 + b_r) * 8192 + ncol]);
  }

  // per-wave stage constants: wave wid stages producers [wid*8, wid*8+8)
  const int myb = lane >> 1;                  // batch row this lane handles
  const int mysw = (myb & 7) << 4;
  const int mybase = myb * 2048 + (lane & 1) * 16;   // LDS dest (untagged 16B half)
  const int srcoff = myb * 64 + (lane & 1) * 32;     // tagged src (32B half of 64B row)

  for (int t = 0; t < 256; t++) {
    const char* tb  = tb_base + (size_t)((t & 1) * 2 + dir) * 131072;
    char* tbn       = tb_base + (size_t)(((t + 1) & 1) * 2 + dir) * 131072;
    const uint32_t exp = (uint32_t)t;

    // ---- stage: one speculative tagged round, then throttled per-chunk retry ----
    {
      int4v v[8][2];
      const char* a0 = tb + srcoff;
#pragma unroll
      for (int j = 0; j < 8; j++) {
        const char* a = a0 + (wid * 8 + j) * 2048;
        asm volatile("global_load_dwordx4 %0, %1, off sc0 sc1" : "=v"(v[j][0]) : "v"(a));
        asm volatile("global_load_dwordx4 %0, %1, off sc0 sc1" : "=v"(v[j][1]) : "v"(a + 16));
      }
      asm volatile("s_waitcnt vmcnt(0)" ::: "memory");
      __builtin_amdgcn_sched_barrier(0);
      int round = 0;
      for (;;) {
        uint32_t bad = 0;
#pragma unroll
        for (int j = 0; j < 8; j++) {
          uint32_t m = (((uint32_t)v[j][0].x ^ exp) | ((uint32_t)v[j][0].y ^ exp) |
                        ((uint32_t)v[j][0].z ^ exp) | ((uint32_t)v[j][0].w ^ exp) |
                        ((uint32_t)v[j][1].x ^ exp) | ((uint32_t)v[j][1].y ^ exp) |
                        ((uint32_t)v[j][1].z ^ exp) | ((uint32_t)v[j][1].w ^ exp)) & 0xffffu;
          if (m) bad |= 1u << j;
        }
        if (!bad) break;
        if (++round > 2) __builtin_amdgcn_s_sleep(8);   // ~0.2us backoff: bounded retry BW
#pragma unroll
        for (int j = 0; j < 8; j++)
          if (bad & (1u << j)) {
            const char* a = a0 + (wid * 8 + j) * 2048;
            asm volatile("global_load_dwordx4 %0, %1, off sc0 sc1" : "=v"(v[j][0]) : "v"(a));
            asm volatile("global_load_dwordx4 %0, %1, off sc0 sc1" : "=v"(v[j][1]) : "v"(a + 16));
          }
        asm volatile("s_waitcnt vmcnt(0)" ::: "memory");
        __builtin_amdgcn_sched_barrier(0);
      }
      __syncthreads();   // all prev-iter Hld MFMA reads complete before overwrite
      // strip tags -> bf16 16B, write LDS (XOR swizzle)
#pragma unroll
      for (int j = 0; j < 8; j++) {
        int4v w;
        w.x = (int)((((uint32_t)v[j][0].x) >> 16) | (((uint32_t)v[j][0].y) & 0xffff0000u));
        w.y = (int)((((uint32_t)v[j][0].z) >> 16) | (((uint32_t)v[j][0].w) & 0xffff0000u));
        w.z = (int)((((uint32_t)v[j][1].x) >> 16) | (((uint32_t)v[j][1].y) & 0xffff0000u));
        w.w = (int)((((uint32_t)v[j][1].z) >> 16) | (((uint32_t)v[j][1].w) & 0xffff0000u));
        int off = (mybase + (wid * 8 + j) * 32) ^ mysw;
        *(int4v*)(Hld + off) = w;
      }
    }
    __syncthreads();

    // ---- two independent MFMA chains ----
    f32x4 accA = (f32x4){0.f, 0.f, 0.f, 0.f};
    f32x4 accB = (f32x4){0.f, 0.f, 0.f, 0.f};
#pragma unroll
    for (int kk = 0; kk < 16; kk++) {
      short8 afA = *(const short8*)(Hld + ((abase + kk * 64) ^ sw));
      short8 afB = *(const short8*)(Hld + ((abase + (kk + 16) * 64) ^ sw));
      accA = __builtin_amdgcn_mfma_f32_16x16x32_bf16(afA, bfr[kk], accA, 0, 0, 0);
      accB = __builtin_amdgcn_mfma_f32_16x16x32_bf16(afB, bfr[kk + 16], accB, 0, 0, 0);
    }

    // ---- gates (fast exp2 math); direct per-wave tagged publish ----
    f32x4 hsave[4];
    const uint32_t tg = (uint32_t)(t + 1);
#pragma unroll
    for (int r = 0; r < 4; r++) {
      int b_r = mt * 16 + lg * 4 + r;
      float z = accA[r] + accB[r] + xg_pf[r];
      float s = (gate == 2) ? tanhfast(z) : sigf(z);
      float x8 = __shfl_xor(s, 8);     // i<->g, f<->o
      float pI = s * x8;               // on i-lanes: sig(i)*tanh(g)
      float v = (gate == 0) ? pI : s;
      float x4 = __shfl_xor(v, 4);     // i-lane receives sig(f)
      float o4 = __shfl_xor(x8, 4);    // i-lane receives sig(o)
      float cn = fmaf(x4, c_reg[r], pI);
      float h = o4 * tanhfast(cn);
      if (c4 < 4) c_reg[r] = cn;
      uint32_t hb16 = (uint32_t)(uint16_t)f2bf(h);
      uint32_t p0 = hb16 | (__shfl_xor(hb16, 1) << 16);
      uint32_t q  = __shfl_xor(p0, 2);
      if (c4 == 0) {
        if (t != 255) {
          int4v e;
          e.x = (int)((p0 << 16) | tg);
          e.y = (int)((p0 & 0xffff0000u) | tg);
          e.z = (int)((q << 16) | tg);
          e.w = (int)((q & 0xffff0000u) | tg);
          char* d = tbn + nblk * 2048 + b_r * 64 + nt * 16;
          asm volatile("global_store_dwordx4 %0, %1, off sc0 sc1" :: "v"(d), "v"(e) : "memory");
        }
        hsave[r].x = bf2f((short)(p0 & 0xffff));
        hsave[r].y = bf2f((short)(p0 >> 16));
        hsave[r].z = bf2f((short)(q & 0xffff));
        hsave[r].w = bf2f((short)(q >> 16));
      }
    }
    // drain publish stores NOW (prompt MALL commit) — per wave, no barrier
    asm volatile("s_waitcnt vmcnt(0)" ::: "memory");
    __builtin_amdgcn_sched_barrier(0);

    // ---- shadow: out stores + XG prefetch t+1 (after commit, off critical path) ----
    if (c4 == 0) {
#pragma unroll
      for (int r = 0; r < 4; r++) {
        int b_r = mt * 16 + lg * 4 + r;
        int tt = (dir == 0) ? t : ((lenv[r] - 1 - t) & 255);
        *(f32x4*)(out + ((size_t)b_r * 256 + tt) * 2048 + dir * 1024 + hcol0) = hsave[r];
      }
    }
    int tn = (t < 255) ? t + 1 : 255;
#pragma unroll
    for (int r = 0; r < 4; r++) {
      int b_r = mt * 16 + lg * 4 + r;
      int tt = (dir == 0) ? tn : ((lenv[r] - 1 - tn) & 255);
      xg_pf[r] = bf2f(XG[(size_t)(tt * 32 + b_r) * 8192 + ncol]);
    }
  }
}

extern "C" void kernel_launch(void* const* d_in, const int* in_sizes, int n_in,
                              void* d_out, int out_size, void* d_ws, size_t ws_size,
                              hipStream_t stream) {
  const float* x    = (const float*)d_in[0];
  const int*   mask = (const int*)d_in[1];
  const float* Wi_f = (const float*)d_in[2];
  const float* Wh_f = (const float*)d_in[3];
  const float* b_f  = (const float*)d_in[4];
  const float* Wi_b = (const float*)d_in[5];
  const float* Wh_b = (const float*)d_in[6];
  const float* b_b  = (const float*)d_in[7];
  float* out = (float*)d_out;
  char* ws = (char*)d_ws;

  short* xbf  = (short*)(ws + OFF_XBF);
  short* WiT  = (short*)(ws + OFF_WIT);
  short* WhT  = (short*)(ws + OFF_WHT);
  short* XG   = (short*)(ws + OFF_XG);
  float* bp   = (float*)(ws + OFF_BIAS);
  int*   len  = (int*)(ws + OFF_LEN);
  unsigned int* htag = (unsigned int*)(ws + OFF_WIT);  // reuses WiT after k_gemm

  k_len<<<1, 64, 0, stream>>>(mask, len);
  k_xconv<<<8192, 256, 0, stream>>>(x, xbf);
  k_wprep<<<4096, 256, 0, stream>>>(Wi_f, Wi_b, Wh_f, Wh_b, WiT, WhT);
  k_bias<<<32, 256, 0, stream>>>(b_f, b_b, bp);

  dim3 g(64, 64);
  k_gemm<<<g, 256, 0, stream>>>(xbf, WiT, bp, XG);

  // WiT dead from here; zero tagged h buffer (tag 0 == step-0, h == 0.0)
  hipMemsetAsync(htag, 0, 524288, stream);

  k_recur<<<128, 512, 0, stream>>>(XG, WhT, len, htag, out);
}